// Round 7
// baseline (343.308 us; speedup 1.0000x reference)
//
#include <hip/hip_runtime.h>

// PIPNet interface scorer: out[p] = W2 . relu(W1 . concat(g1[il[p]], g2[ir[p]]) + b1) + b2
// Overhead model (R2/R4/R5/R6 reconciled): harness adds a FIXED ~175-180us
// regardless of ws_size. Controllable time = w1_frag (~3us) + main.
// R6: f32-direct gather, per-wave-private LDS (no __syncthreads), main=160us,
//     FETCH=251MB (= compulsory unique rows; L3 absorbs all re-reads),
//     1.6 TB/s, VGPR=48 -> latency-bound: too few regs to keep loads in flight.
// R7: (a) register-batched gather: 2 batches x 8 float4 loads held in regs
//     before convert+LDS-write -> 8 outstanding vmem/wave.
//     (b) nt-sequential compute: acc = one 32x32 block (16 AGPR, was 64);
//     separable epilogue sacc[r] += relu(acc[r]+b1[nt])*w2[nt], identical FP
//     order. Frees the regs that (a) needs; costs 24 extra ds_read_b128/wave.

typedef __bf16 bf16x8 __attribute__((ext_vector_type(8)));
typedef float f32x16 __attribute__((ext_vector_type(16)));

__device__ __forceinline__ unsigned f2bf(float f) {
  union { float f; unsigned u; } v;
  v.f = f;
  unsigned u = v.u;
  return (u + 0x7fffu + ((u >> 16) & 1u)) >> 16;  // RNE f32->bf16
}

// W1 [128x128] f32 row-major -> bf16 B-fragments for v_mfma_f32_32x32x16_bf16.
// Fragment (ks, nt, lane): n = lane&31, h = lane>>5;
//   elements = W1[nt*32+n][ks*16 + h*8 + j], j = 0..7
__global__ __launch_bounds__(256) void w1_frag_kernel(
    const float* __restrict__ W1, uint4* __restrict__ w1f) {
  int t = blockIdx.x * 256 + threadIdx.x;  // 0..2047
  int lane = t & 63;
  int nt = (t >> 6) & 3;
  int ks = t >> 8;
  int n = lane & 31, h = lane >> 5;
  const float4* src =
      (const float4*)(W1 + ((nt * 32 + n) * 128 + ks * 16 + h * 8));
  float4 a = src[0], b = src[1];
  uint4 o;
  o.x = f2bf(a.x) | (f2bf(a.y) << 16);
  o.y = f2bf(a.z) | (f2bf(a.w) << 16);
  o.z = f2bf(b.x) | (f2bf(b.y) << 16);
  o.w = f2bf(b.z) | (f2bf(b.w) << 16);
  w1f[t] = o;
}

// LDS: 4 waves x 8192 B (32 local pairs x 256 B), wave-private regions.
// Row pl holds the 128 bf16 concat features as 16B granules at
// phys = (g16 ^ (pl&7))<<4  (R5/R6-verified swizzle).
__global__ __launch_bounds__(256, 4) void pip_main_kernel(
    const float* __restrict__ g1, const float* __restrict__ g2,
    const int* __restrict__ il, const int* __restrict__ ir,
    const bf16x8* __restrict__ w1f,
    const float* __restrict__ b1, const float* __restrict__ w2,
    const float* __restrict__ b2,
    float* __restrict__ out, int P) {
  __shared__ unsigned char A[4][8192];  // 32768 B total

  const int t = threadIdx.x;
  const int lane = t & 63;
  const int w = t >> 6;
  const int pair0 = blockIdx.x * 128;

  // ---- Per-wave gather: 16 lanes per 256B f32 row; rounds cover the wave's
  // 64 rows (32 pairs x 2 sides). Group g = lane>>4: side = g&1 (fixed),
  // local pair for round j = j*2 + (g>>1).
  const int sub = lane & 15;     // lane's 16B f32 slice within the 256B row
  const int g = lane >> 4;       // 0..3
  const int side = g & 1;        // 0: left/g1, 1: right/g2
  const int phalf = g >> 1;      // 0..1
  const float* feat = side ? g2 : g1;
  const int* idxarr = side ? ir : il;

  int idxv[16];
#pragma unroll
  for (int j = 0; j < 16; ++j) {
    int gp = pair0 + w * 32 + j * 2 + phalf;
    int pidx = (gp < P) ? gp : (P - 1);
    idxv[j] = idxarr[pidx];
  }

  unsigned char* Aw = &A[w][0];
  const int g16 = side * 8 + (sub >> 1);  // logical 16B granule 0..15
#pragma unroll
  for (int b = 0; b < 2; ++b) {
    // Batch: issue 8 independent gather loads into registers, THEN convert
    // and write to LDS. Keeps 8 vmem in flight per wave.
    float4 vv[8];
#pragma unroll
    for (int j = 0; j < 8; ++j) {
      vv[j] =
          *(const float4*)(feat + (size_t)idxv[b * 8 + j] * 64 + sub * 4);
    }
#pragma unroll
    for (int j = 0; j < 8; ++j) {
      int pl = (b * 8 + j) * 2 + phalf;  // local pair 0..31
      unsigned lo = f2bf(vv[j].x) | (f2bf(vv[j].y) << 16);
      unsigned hi = f2bf(vv[j].z) | (f2bf(vv[j].w) << 16);
      *(uint2*)(Aw + pl * 256 + ((g16 ^ (pl & 7)) << 4) + ((sub & 1) << 3)) =
          make_uint2(lo, hi);
    }
  }
  // Wave-private region: only this wave reads what it wrote; drain LDS writes.
  asm volatile("s_waitcnt lgkmcnt(0)" ::: "memory");

  // ---- Compute: wave w handles pairs [w*32, w*32+32), n processed in four
  // sequential 32-wide blocks (nt) to keep the accumulator at 16 regs.
  const int n = lane & 31;   // MFMA m/n index within tile (= local pair)
  const int h = lane >> 5;

  const unsigned char* Abase = Aw + n * 256;
  const int rk = n & 7;  // = local pair & 7

  float sacc[16];
#pragma unroll
  for (int i = 0; i < 16; ++i) sacc[i] = 0.0f;
  const float bias2 = b2[0];

#pragma unroll 1
  for (int nt = 0; nt < 4; ++nt) {
    const float b1v = b1[nt * 32 + n];
    const float w2v = w2[nt * 32 + n];
    f32x16 acc;
#pragma unroll
    for (int i = 0; i < 16; ++i) acc[i] = 0.0f;
#pragma unroll
    for (int ks = 0; ks < 8; ++ks) {
      bf16x8 af = *(const bf16x8*)(Abase + (((ks * 2 + h) ^ rk) << 4));
      bf16x8 bfr = w1f[(ks * 4 + nt) * 64 + lane];
      acc = __builtin_amdgcn_mfma_f32_32x32x16_bf16(af, bfr, acc, 0, 0, 0);
    }
    // Separable epilogue piece: same FP order as the R6 epilogue's nt-inner
    // loop (nt = 0..3 accumulated into s before the shuffle reduce).
#pragma unroll
    for (int r = 0; r < 16; ++r) {
      float v = fmaxf(acc[r] + b1v, 0.0f);
      sacc[r] = fmaf(v, w2v, sacc[r]);
    }
  }

  // ---- Final reduce + store: C/D layout col(n)=lane&31,
  // row(m) = (r&3) + 8*(r>>2) + 4*h.
#pragma unroll
  for (int r = 0; r < 16; ++r) {
    float s = sacc[r];
    s += __shfl_xor(s, 1);
    s += __shfl_xor(s, 2);
    s += __shfl_xor(s, 4);
    s += __shfl_xor(s, 8);
    s += __shfl_xor(s, 16);
    if (n == 0) {
      int row = (r & 3) + 8 * (r >> 2) + 4 * h;
      int gp = pair0 + w * 32 + row;
      if (gp < P) out[gp] = s + bias2;
    }
  }
}

extern "C" void kernel_launch(void* const* d_in, const int* in_sizes, int n_in,
                              void* d_out, int out_size, void* d_ws, size_t ws_size,
                              hipStream_t stream) {
  const float* g1 = (const float*)d_in[0];   // graph1_x [N,64] f32
  const float* g2 = (const float*)d_in[1];   // graph2_x [N,64] f32
  const int* il = (const int*)d_in[2];       // idx_left [P] int32
  const int* ir = (const int*)d_in[3];       // idx_right [P] int32
  const float* W1 = (const float*)d_in[4];   // [128,128]
  const float* b1 = (const float*)d_in[5];   // [128]
  const float* w2 = (const float*)d_in[6];   // [1,128]
  const float* b2 = (const float*)d_in[7];   // [1]
  float* out = (float*)d_out;                // [P,1] f32
  const int P = out_size;                    // element count

  // d_ws: only 32 KB of bf16 W1 B-fragments (rebuilt every call).
  w1_frag_kernel<<<8, 256, 0, stream>>>(W1, (uint4*)d_ws);

  const int nblocks = (P + 127) / 128;
  pip_main_kernel<<<nblocks, 256, 0, stream>>>(
      g1, g2, il, ir, (const bf16x8*)d_ws, b1, w2, b2, out, P);
}